// Round 8
// baseline (542.424 us; speedup 1.0000x reference)
//
#include <hip/hip_runtime.h>

#define NB 8
#define NT 400
#define NN 200
#define ND 80
#define NROWS (NB * NT * NN)
#define PRODB (NROWS / 64)   // 10000 producer blocks

static constexpr float BIG_NEG = -1e30f;
static constexpr float LN2 = 0.6931471805599453f;
static constexpr float LOG2E = 1.4426950408889634f;
static constexpr float L2EPS = -99.65784284662087f;        // log(1e-30)*LOG2E
static constexpr float HALF_LOG2E = 0.7213475204444817f;   // 0.5*LOG2E
static constexpr float D_HALF_L2PI = 106.05984517680935f;  // D*0.5*log2(2pi)

#define A_LDU(p)    __hip_atomic_load((p), __ATOMIC_RELAXED, __HIP_MEMORY_SCOPE_AGENT)
#define A_STF(p, v) __hip_atomic_store((p), (v), __ATOMIC_RELAXED, __HIP_MEMORY_SCOPE_AGENT)
#define A_ADD(p, v) (void)__hip_atomic_fetch_add((p), (v), __ATOMIC_RELEASE, __HIP_MEMORY_SCOPE_AGENT)

static __device__ __forceinline__ float hw_exp2(float x) { return __builtin_amdgcn_exp2f(x); }
static __device__ __forceinline__ float hw_log2(float x) { return __builtin_amdgcn_logf(x); }

// exact log2(2^a + 2^b); a,b finite, possibly ~ -1e30
static __device__ __forceinline__ float l2add(float a, float b) {
    float mx = fmaxf(a, b);
    float d = fminf(a, b) - mx;  // <= 0
    return mx + hw_log2(1.0f + hw_exp2(d));
}

// log2(1 + 2^-|w|), in [0,1]
static __device__ __forceinline__ float softplus2(float w) {
    return hw_log2(1.0f + hw_exp2(-fabsf(w)));
}

// whole-wave shift right by 1 lane via DPP; lane 0 receives `fill`
static __device__ __forceinline__ float wave_shr1(float x, float fill) {
    int r = __builtin_amdgcn_update_dpp(__float_as_int(fill), __float_as_int(x),
                                        0x138 /*wave_shr:1*/, 0xF, 0xF, false);
    return __int_as_float(r);
}

// ---------------------------------------------------------------------------
// Fused producer/consumer.
// Blocks 0..7: scanners (one wave per b), dispatched first.
// Blocks 8..: producers in (t,b,n)-major order -> the t-frontier advances
// uniformly across all b, so every scanner streams concurrently.
// Producers: emission+transition fold, agent-scope stores (visible at L3),
// then per-(t,b)-group flag atomicAdd (release) after __syncthreads.
// Scanners: spin on flags one 8-window ahead (relaxed atomic u32 loads),
// read SE/ME with PLAIN float4 loads (local caches hold no stale copies:
// kernel-start invalidate + unique-writer agent stores), depth-8 pipeline
// (~30 outstanding vmem ops, well under the 63-entry vmcnt window).
// ---------------------------------------------------------------------------
__global__ __launch_bounds__(256, 5) void fused_kernel(
    const float* __restrict__ mels,   // (B,T,D)
    const float* __restrict__ means,  // (B,T,N,D)
    const float* __restrict__ stds,   // (B,T,N,D)
    const float* __restrict__ tv,     // (B,T,N)
    const int* __restrict__ inputs_len,
    const int* __restrict__ mel_lens,
    float* __restrict__ SE,           // (B,T,N) ws
    float* __restrict__ ME,           // (B,T,N) ws
    unsigned* __restrict__ flags,     // (T,B) ws, pre-zeroed; idx = t*NB+b
    float* __restrict__ out)          // (B,)
{
    if (blockIdx.x >= NB) {
        // ----------------------------- producer -----------------------------
        const int tid = threadIdx.x;
        const int G = (blockIdx.x - NB) * 64 + (tid >> 2);  // (t,b,n)-major row
        const int q = tid & 3;
        const int t = G / (NB * NN);
        const int rb = G - t * (NB * NN);
        const int b = rb / NN;
        const int n = rb - b * NN;
        const int ml = mel_lens[b];
        const int il = inputs_len[b];
        const int R = (b * NT + t) * NN + n;                // (b,t,n) storage idx

        if (t < ml) {
            if (n >= il) {
                if (q == 0) { A_STF(&SE[R], BIG_NEG); A_STF(&ME[R], BIG_NEG); }
            } else {
                const float4* mp = reinterpret_cast<const float4*>(means) + (size_t)R * (ND / 4) + q;
                const float4* sp = reinterpret_cast<const float4*>(stds)  + (size_t)R * (ND / 4) + q;
                const float4* xp = reinterpret_cast<const float4*>(mels)  + (size_t)(b * NT + t) * (ND / 4) + q;
                float acc = 0.f;    // sum z^2
                float prod = 1.f;   // prod of 20 stds in [9.5e-7, 3325]: safe
#pragma unroll
                for (int k = 0; k < ND / 16; ++k) {
                    const float4 m = mp[k * 4];
                    const float4 s = sp[k * 4];
                    const float4 x = xp[k * 4];
                    float z0 = __fdividef(x.x - m.x, s.x);
                    float z1 = __fdividef(x.y - m.y, s.y);
                    float z2 = __fdividef(x.z - m.z, s.z);
                    float z3 = __fdividef(x.w - m.w, s.w);
                    acc = fmaf(z0, z0, acc);
                    acc = fmaf(z1, z1, acc);
                    acc = fmaf(z2, z2, acc);
                    acc = fmaf(z3, z3, acc);
                    prod *= s.x * s.y * s.z * s.w;
                }
                acc = fmaf(acc, HALF_LOG2E, hw_log2(prod));
                acc += __shfl_xor(acc, 1);
                acc += __shfl_xor(acc, 2);
                if (q == 0) {
                    const float e2 = -acc - D_HALF_L2PI;
                    if (t == 0) {
                        A_STF(&SE[R], e2);        // raw e2; only n==0 consumed
                        A_STF(&ME[R], BIG_NEG);
                    } else {
                        float w = tv[R] * LOG2E;
                        float stay2 = -(fmaxf(w, 0.f) + softplus2(w));     // log2 sig(-v)
                        A_STF(&SE[R], e2 + fmaxf(stay2, L2EPS));
                        if (n == 0) {
                            A_STF(&ME[R], BIG_NEG);
                        } else {
                            float u = tv[R - 1] * LOG2E;
                            float mv2 = -(fmaxf(-u, 0.f) + softplus2(u));  // log2 sig(v)
                            A_STF(&ME[R], e2 + fmaxf(mv2, L2EPS));
                        }
                    }
                }
            }
        }
        __syncthreads();   // compiler drains vmcnt(0) before s_barrier -> stores done
        if (tid == 0) {
            const int G0 = (blockIdx.x - NB) * 64;
            const int g0 = G0 / NN, g1 = (G0 + 63) / NN;   // (t*NB+b) group ids
            if (g0 == g1) {
                A_ADD(&flags[g0], 64u);
            } else {
                unsigned c0 = (unsigned)((g0 + 1) * NN - G0);
                A_ADD(&flags[g0], c0);
                A_ADD(&flags[g1], 64u - c0);
            }
        }
        return;
    }

    // ------------------------------- scanner --------------------------------
    const int b = blockIdx.x;
    if (threadIdx.x >= 64) return;
    const int lane = threadIdx.x;
    const int il = inputs_len[b];
    const int ml = mel_lens[b];
    const int mlm1 = ml - 1;
    const int cl = (lane < NN / 4) ? lane : (NN / 4 - 1);

    const float* seb = SE + (size_t)b * NT * NN;
    const float* meb = ME + (size_t)b * NT * NN;
    const float* vb  = tv + (size_t)b * NT * NN;
    unsigned* flgb = flags + b;            // flag for time T at flgb[T*NB]

    unsigned fv0, fv1, fv2, fv3, fv4, fv5, fv6, fv7;
#define FLD(K, TT) fv##K = ((TT) < ml) ? A_LDU(flgb + (size_t)(TT) * NB) : (unsigned)NN;
#define FCHK(K, TT) if ((TT) < ml) { while (fv##K < (unsigned)NN) fv##K = A_LDU(flgb + (size_t)(TT) * NB); }
#define F8(OP, T0) OP(0,(T0)) OP(1,(T0)+1) OP(2,(T0)+2) OP(3,(T0)+3) \
                   OP(4,(T0)+4) OP(5,(T0)+5) OP(6,(T0)+6) OP(7,(T0)+7)

    // prologue: confirm flags 0..8, leave fv = loaded flags [9,17)
    F8(FLD, 0) F8(FCHK, 0)
    FLD(0, 8) FCHK(0, 8)
    asm volatile("" ::: "memory");
    F8(FLD, 9)

    auto ld4 = [cl](const float* p) { return reinterpret_cast<const float4*>(p)[cl]; };
#define LDT(TT) ((size_t)(((TT) <= mlm1) ? (TT) : mlm1) * NN)

    // depth-8 slots: slot K holds t = base+K, base starts at 1 (ml >= 200)
#define PREL(K, TT) \
    float4 se##K = ld4(seb + LDT(TT)); \
    float4 me##K = ld4(meb + LDT(TT));
    PREL(0, 1) PREL(1, 2) PREL(2, 3) PREL(3, 4)
    PREL(4, 5) PREL(5, 6) PREL(6, 7) PREL(7, 8)
#undef PREL

    // init t=0: only state 0 finite (prior); SE[b][0][0] holds raw e2
    float la0 = (lane == 0) ? seb[0] : BIG_NEG;
    float la1 = BIG_NEG, la2 = BIG_NEG, la3 = BIG_NEG;

#define STEPBODY(SEV, MEV) { \
        float carry = wave_shr1(la3, BIG_NEG); \
        float a0 = la0 + SEV.x, c0 = carry + MEV.x; \
        float a1 = la1 + SEV.y, c1 = la0 + MEV.y; \
        float a2 = la2 + SEV.z, c2 = la1 + MEV.z; \
        float a3 = la3 + SEV.w, c3 = la2 + MEV.w; \
        la0 = l2add(a0, c0); la1 = l2add(a1, c1); \
        la2 = l2add(a2, c2); la3 = l2add(a3, c3); }

#define STEP(K, TT) { \
        float4 se_ = se##K, me_ = me##K; \
        se##K = ld4(seb + LDT((TT) + 8)); \
        me##K = ld4(meb + LDT((TT) + 8)); \
        STEPBODY(se_, me_) }

#define TSTEP(K) if (t + (K) < ml) { STEPBODY(se##K, me##K) }

    int t = 1;
    for (; t + 7 < ml; t += 8) {
        // confirm flags [t+8, t+16) (loaded one window ago), then issue [t+16, t+24)
        F8(FCHK, t + 8)
        asm volatile("" ::: "memory");
        F8(FLD, t + 16)
        STEP(0, t)     STEP(1, t + 1) STEP(2, t + 2) STEP(3, t + 3)
        STEP(4, t + 4) STEP(5, t + 5) STEP(6, t + 6) STEP(7, t + 7)
    }
    // tail (<= 7 steps): slots hold t..t+7, flags already confirmed
    TSTEP(0) TSTEP(1) TSTEP(2) TSTEP(3) TSTEP(4) TSTEP(5) TSTEP(6)

#undef FLD
#undef FCHK
#undef F8
#undef LDT
#undef STEPBODY
#undef STEP
#undef TSTEP

    // final: only state il-1 contributes
    const int fin = il - 1;
    const int n0 = lane * 4;
    if (fin >= n0 && fin < n0 + 4) {
        float w = vb[(size_t)mlm1 * NN + fin] * LOG2E;
        float lmove2 = fmaxf(-(fmaxf(-w, 0.f) + softplus2(w)), L2EPS);
        float lastla = (fin == n0)     ? la0
                     : (fin == n0 + 1) ? la1
                     : (fin == n0 + 2) ? la2
                                       : la3;
        out[b] = LN2 * (lastla + lmove2);
    }
}

extern "C" void kernel_launch(void* const* d_in, const int* in_sizes, int n_in,
                              void* d_out, int out_size, void* d_ws, size_t ws_size,
                              hipStream_t stream) {
    const float* mels  = (const float*)d_in[0];
    const float* means = (const float*)d_in[1];
    const float* stds  = (const float*)d_in[2];
    const float* tv    = (const float*)d_in[3];
    const int* inputs_len = (const int*)d_in[4];
    const int* mel_lens   = (const int*)d_in[5];
    float* out = (float*)d_out;

    float* SE = (float*)d_ws;                           // B*T*N floats
    float* ME = SE + (size_t)NROWS;                     // B*T*N floats
    unsigned* flags = (unsigned*)(ME + (size_t)NROWS);  // T*B uints (12.8 KB)

    hipMemsetAsync(flags, 0, (size_t)NT * NB * sizeof(unsigned), stream);
    fused_kernel<<<dim3(PRODB + NB), dim3(256), 0, stream>>>(
        mels, means, stds, tv, inputs_len, mel_lens, SE, ME, flags, out);
}

// Round 9
// 183.565 us; speedup vs baseline: 2.9549x; 2.9549x over previous
//
#include <hip/hip_runtime.h>

#define NB 8
#define NT 400
#define NN 200
#define ND 80
#define NROWS (NB * NT * NN)
#define PRODB (NROWS / 64)   // 10000 producer blocks

static constexpr float BIG_NEG = -1e30f;
static constexpr float LN2 = 0.6931471805599453f;
static constexpr float LOG2E = 1.4426950408889634f;
static constexpr float L2EPS = -99.65784284662087f;        // log(1e-30)*LOG2E
static constexpr float HALF_LOG2E = 0.7213475204444817f;   // 0.5*LOG2E
static constexpr float D_HALF_L2PI = 106.05984517680935f;  // D*0.5*log2(2pi)

// All RELAXED. The producer's __syncthreads() drains vmcnt(0), which means the
// sc1 (agent-scope, LLC-write-through) SE/ME stores are ACKed at the coherence
// point before the flag add issues. RELEASE here emits buffer_wbl2 (full XCD-L2
// writeback) per block -- the R8 700us pathology. Do NOT use release.
#define A_LDU(p)    __hip_atomic_load((p), __ATOMIC_RELAXED, __HIP_MEMORY_SCOPE_AGENT)
#define A_STF(p, v) __hip_atomic_store((p), (v), __ATOMIC_RELAXED, __HIP_MEMORY_SCOPE_AGENT)
#define A_ADD(p, v) (void)__hip_atomic_fetch_add((p), (v), __ATOMIC_RELAXED, __HIP_MEMORY_SCOPE_AGENT)

static __device__ __forceinline__ float hw_exp2(float x) { return __builtin_amdgcn_exp2f(x); }
static __device__ __forceinline__ float hw_log2(float x) { return __builtin_amdgcn_logf(x); }

// exact log2(2^a + 2^b); a,b finite, possibly ~ -1e30
static __device__ __forceinline__ float l2add(float a, float b) {
    float mx = fmaxf(a, b);
    float d = fminf(a, b) - mx;  // <= 0
    return mx + hw_log2(1.0f + hw_exp2(d));
}

// log2(1 + 2^-|w|), in [0,1]
static __device__ __forceinline__ float softplus2(float w) {
    return hw_log2(1.0f + hw_exp2(-fabsf(w)));
}

// whole-wave shift right by 1 lane via DPP; lane 0 receives `fill`
static __device__ __forceinline__ float wave_shr1(float x, float fill) {
    int r = __builtin_amdgcn_update_dpp(__float_as_int(fill), __float_as_int(x),
                                        0x138 /*wave_shr:1*/, 0xF, 0xF, false);
    return __int_as_float(r);
}

// ---------------------------------------------------------------------------
// Fused producer/consumer.
// Blocks 0..7: scanners (one wave per b), dispatched first.
// Blocks 8..: producers in (t,b,n)-major order -> the t-frontier advances
// uniformly across all b, so every scanner streams concurrently.
// Producers: emission+transition fold, agent-scope (sc1) stores -> LLC,
// __syncthreads (drains vmcnt), then RELAXED per-(t,b) flag atomicAdd.
// Scanners: spin on flags one 8-window ahead (relaxed agent loads), read
// SE/ME with PLAIN float4 loads (scanner L2 starts invalidated at kernel
// launch and lines are only pulled after the flag confirms -> always fresh
// from LLC), depth-8 register pipeline (~32 outstanding vmem < 63 window).
// ---------------------------------------------------------------------------
__global__ __launch_bounds__(256, 5) void fused_kernel(
    const float* __restrict__ mels,   // (B,T,D)
    const float* __restrict__ means,  // (B,T,N,D)
    const float* __restrict__ stds,   // (B,T,N,D)
    const float* __restrict__ tv,     // (B,T,N)
    const int* __restrict__ inputs_len,
    const int* __restrict__ mel_lens,
    float* __restrict__ SE,           // (B,T,N) ws
    float* __restrict__ ME,           // (B,T,N) ws
    unsigned* __restrict__ flags,     // (T,B) ws, pre-zeroed; idx = t*NB+b
    float* __restrict__ out)          // (B,)
{
    if (blockIdx.x >= NB) {
        // ----------------------------- producer -----------------------------
        const int tid = threadIdx.x;
        const int G = (blockIdx.x - NB) * 64 + (tid >> 2);  // (t,b,n)-major row
        const int q = tid & 3;
        const int t = G / (NB * NN);
        const int rb = G - t * (NB * NN);
        const int b = rb / NN;
        const int n = rb - b * NN;
        const int ml = mel_lens[b];
        const int il = inputs_len[b];
        const int R = (b * NT + t) * NN + n;                // (b,t,n) storage idx

        if (t < ml) {
            if (n >= il) {
                if (q == 0) { A_STF(&SE[R], BIG_NEG); A_STF(&ME[R], BIG_NEG); }
            } else {
                const float4* mp = reinterpret_cast<const float4*>(means) + (size_t)R * (ND / 4) + q;
                const float4* sp = reinterpret_cast<const float4*>(stds)  + (size_t)R * (ND / 4) + q;
                const float4* xp = reinterpret_cast<const float4*>(mels)  + (size_t)(b * NT + t) * (ND / 4) + q;
                float acc = 0.f;    // sum z^2
                float prod = 1.f;   // prod of 20 stds in [9.5e-7, 3325]: safe
#pragma unroll
                for (int k = 0; k < ND / 16; ++k) {
                    const float4 m = mp[k * 4];
                    const float4 s = sp[k * 4];
                    const float4 x = xp[k * 4];
                    float z0 = __fdividef(x.x - m.x, s.x);
                    float z1 = __fdividef(x.y - m.y, s.y);
                    float z2 = __fdividef(x.z - m.z, s.z);
                    float z3 = __fdividef(x.w - m.w, s.w);
                    acc = fmaf(z0, z0, acc);
                    acc = fmaf(z1, z1, acc);
                    acc = fmaf(z2, z2, acc);
                    acc = fmaf(z3, z3, acc);
                    prod *= s.x * s.y * s.z * s.w;
                }
                acc = fmaf(acc, HALF_LOG2E, hw_log2(prod));
                acc += __shfl_xor(acc, 1);
                acc += __shfl_xor(acc, 2);
                if (q == 0) {
                    const float e2 = -acc - D_HALF_L2PI;
                    if (t == 0) {
                        A_STF(&SE[R], e2);        // raw e2; only n==0 consumed
                        A_STF(&ME[R], BIG_NEG);
                    } else {
                        float w = tv[R] * LOG2E;
                        float stay2 = -(fmaxf(w, 0.f) + softplus2(w));     // log2 sig(-v)
                        A_STF(&SE[R], e2 + fmaxf(stay2, L2EPS));
                        if (n == 0) {
                            A_STF(&ME[R], BIG_NEG);
                        } else {
                            float u = tv[R - 1] * LOG2E;
                            float mv2 = -(fmaxf(-u, 0.f) + softplus2(u));  // log2 sig(v)
                            A_STF(&ME[R], e2 + fmaxf(mv2, L2EPS));
                        }
                    }
                }
            }
        }
        __syncthreads();   // s_waitcnt vmcnt(0) before s_barrier -> sc1 stores at LLC
        if (tid == 0) {
            const int G0 = (blockIdx.x - NB) * 64;
            const int g0 = G0 / NN, g1 = (G0 + 63) / NN;   // (t*NB+b) group ids
            if (g0 == g1) {
                A_ADD(&flags[g0], 64u);
            } else {
                unsigned c0 = (unsigned)((g0 + 1) * NN - G0);
                A_ADD(&flags[g0], c0);
                A_ADD(&flags[g1], 64u - c0);
            }
        }
        return;
    }

    // ------------------------------- scanner --------------------------------
    const int b = blockIdx.x;
    if (threadIdx.x >= 64) return;
    const int lane = threadIdx.x;
    const int il = inputs_len[b];
    const int ml = mel_lens[b];
    const int mlm1 = ml - 1;
    const int cl = (lane < NN / 4) ? lane : (NN / 4 - 1);

    const float* seb = SE + (size_t)b * NT * NN;
    const float* meb = ME + (size_t)b * NT * NN;
    const float* vb  = tv + (size_t)b * NT * NN;
    unsigned* flgb = flags + b;            // flag for time T at flgb[T*NB]

    unsigned fv0, fv1, fv2, fv3, fv4, fv5, fv6, fv7;
#define FLD(K, TT) fv##K = ((TT) < ml) ? A_LDU(flgb + (size_t)(TT) * NB) : (unsigned)NN;
#define FCHK(K, TT) if ((TT) < ml) { while (fv##K < (unsigned)NN) fv##K = A_LDU(flgb + (size_t)(TT) * NB); }
#define F8(OP, T0) OP(0,(T0)) OP(1,(T0)+1) OP(2,(T0)+2) OP(3,(T0)+3) \
                   OP(4,(T0)+4) OP(5,(T0)+5) OP(6,(T0)+6) OP(7,(T0)+7)

    // prologue: confirm flags 0..8, leave fv = loaded flags [9,17)
    F8(FLD, 0) F8(FCHK, 0)
    FLD(0, 8) FCHK(0, 8)
    asm volatile("" ::: "memory");
    F8(FLD, 9)

    auto ld4 = [cl](const float* p) { return reinterpret_cast<const float4*>(p)[cl]; };
#define LDT(TT) ((size_t)(((TT) <= mlm1) ? (TT) : mlm1) * NN)

    // depth-8 slots: slot K holds t = base+K, base starts at 1 (ml >= 200)
#define PREL(K, TT) \
    float4 se##K = ld4(seb + LDT(TT)); \
    float4 me##K = ld4(meb + LDT(TT));
    PREL(0, 1) PREL(1, 2) PREL(2, 3) PREL(3, 4)
    PREL(4, 5) PREL(5, 6) PREL(6, 7) PREL(7, 8)
#undef PREL

    // init t=0: only state 0 finite (prior); SE[b][0][0] holds raw e2
    float la0 = (lane == 0) ? seb[0] : BIG_NEG;
    float la1 = BIG_NEG, la2 = BIG_NEG, la3 = BIG_NEG;

#define STEPBODY(SEV, MEV) { \
        float carry = wave_shr1(la3, BIG_NEG); \
        float a0 = la0 + SEV.x, c0 = carry + MEV.x; \
        float a1 = la1 + SEV.y, c1 = la0 + MEV.y; \
        float a2 = la2 + SEV.z, c2 = la1 + MEV.z; \
        float a3 = la3 + SEV.w, c3 = la2 + MEV.w; \
        la0 = l2add(a0, c0); la1 = l2add(a1, c1); \
        la2 = l2add(a2, c2); la3 = l2add(a3, c3); }

#define STEP(K, TT) { \
        float4 se_ = se##K, me_ = me##K; \
        se##K = ld4(seb + LDT((TT) + 8)); \
        me##K = ld4(meb + LDT((TT) + 8)); \
        STEPBODY(se_, me_) }

#define TSTEP(K) if (t + (K) < ml) { STEPBODY(se##K, me##K) }

    int t = 1;
    for (; t + 7 < ml; t += 8) {
        // confirm flags [t+8, t+16) (loaded one window ago), then issue [t+16, t+24)
        F8(FCHK, t + 8)
        asm volatile("" ::: "memory");
        F8(FLD, t + 16)
        STEP(0, t)     STEP(1, t + 1) STEP(2, t + 2) STEP(3, t + 3)
        STEP(4, t + 4) STEP(5, t + 5) STEP(6, t + 6) STEP(7, t + 7)
    }
    // tail (<= 7 steps): slots hold t..t+7, flags already confirmed
    TSTEP(0) TSTEP(1) TSTEP(2) TSTEP(3) TSTEP(4) TSTEP(5) TSTEP(6)

#undef FLD
#undef FCHK
#undef F8
#undef LDT
#undef STEPBODY
#undef STEP
#undef TSTEP

    // final: only state il-1 contributes
    const int fin = il - 1;
    const int n0 = lane * 4;
    if (fin >= n0 && fin < n0 + 4) {
        float w = vb[(size_t)mlm1 * NN + fin] * LOG2E;
        float lmove2 = fmaxf(-(fmaxf(-w, 0.f) + softplus2(w)), L2EPS);
        float lastla = (fin == n0)     ? la0
                     : (fin == n0 + 1) ? la1
                     : (fin == n0 + 2) ? la2
                                       : la3;
        out[b] = LN2 * (lastla + lmove2);
    }
}

extern "C" void kernel_launch(void* const* d_in, const int* in_sizes, int n_in,
                              void* d_out, int out_size, void* d_ws, size_t ws_size,
                              hipStream_t stream) {
    const float* mels  = (const float*)d_in[0];
    const float* means = (const float*)d_in[1];
    const float* stds  = (const float*)d_in[2];
    const float* tv    = (const float*)d_in[3];
    const int* inputs_len = (const int*)d_in[4];
    const int* mel_lens   = (const int*)d_in[5];
    float* out = (float*)d_out;

    float* SE = (float*)d_ws;                           // B*T*N floats
    float* ME = SE + (size_t)NROWS;                     // B*T*N floats
    unsigned* flags = (unsigned*)(ME + (size_t)NROWS);  // T*B uints (12.8 KB)

    hipMemsetAsync(flags, 0, (size_t)NT * NB * sizeof(unsigned), stream);
    fused_kernel<<<dim3(PRODB + NB), dim3(256), 0, stream>>>(
        mels, means, stds, tv, inputs_len, mel_lens, SE, ME, flags, out);
}

// Round 10
// 139.222 us; speedup vs baseline: 3.8961x; 1.3185x over previous
//
#include <hip/hip_runtime.h>

#define NB 8
#define NT 400
#define NN 200
#define ND 80
#define NROWS (NB * NT * NN)
#define PRODB (NROWS / 64)   // 10000 producer blocks

static constexpr float BIG_NEG = -1e30f;
static constexpr float LN2 = 0.6931471805599453f;
static constexpr float LOG2E = 1.4426950408889634f;
static constexpr float L2EPS = -99.65784284662087f;        // log(1e-30)*LOG2E
static constexpr float HALF_LOG2E = 0.7213475204444817f;   // 0.5*LOG2E
static constexpr float D_HALF_L2PI = 106.05984517680935f;  // D*0.5*log2(2pi)

// Producer side: RELAXED everywhere. RELEASE emits buffer_wbl2 (full XCD-L2
// writeback) per block = the R8 700us pathology. Visibility chain instead:
// sc1 stores -> __syncthreads drains vmcnt(0) (stores ACKed at LLC) -> flag add.
#define A_STF(p, v) __hip_atomic_store((p), (v), __ATOMIC_RELAXED, __HIP_MEMORY_SCOPE_AGENT)
#define A_ADD(p, v) (void)__hip_atomic_fetch_add((p), (v), __ATOMIC_RELAXED, __HIP_MEMORY_SCOPE_AGENT)
// Scanner flag reads: MUST be RMW, not atomic load. A relaxed agent LOAD can be
// served from the scanner XCD's own L2, which holds a STALE copy (the scanner
// touched the flag line before the producer wrote it; producer updates hit the
// LLC but don't invalidate remote L2s) -> spin until eviction = the R5/R9
// multi-us-per-window crawl. A fetch_add(0) executes at the coherence point.
#define A_RMW0(p) __hip_atomic_fetch_add((p), 0u, __ATOMIC_RELAXED, __HIP_MEMORY_SCOPE_AGENT)

static __device__ __forceinline__ float hw_exp2(float x) { return __builtin_amdgcn_exp2f(x); }
static __device__ __forceinline__ float hw_log2(float x) { return __builtin_amdgcn_logf(x); }

// exact log2(2^a + 2^b); a,b finite, possibly ~ -1e30
static __device__ __forceinline__ float l2add(float a, float b) {
    float mx = fmaxf(a, b);
    float d = fminf(a, b) - mx;  // <= 0
    return mx + hw_log2(1.0f + hw_exp2(d));
}

// log2(1 + 2^-|w|), in [0,1]
static __device__ __forceinline__ float softplus2(float w) {
    return hw_log2(1.0f + hw_exp2(-fabsf(w)));
}

// whole-wave shift right by 1 lane via DPP; lane 0 receives `fill`
static __device__ __forceinline__ float wave_shr1(float x, float fill) {
    int r = __builtin_amdgcn_update_dpp(__float_as_int(fill), __float_as_int(x),
                                        0x138 /*wave_shr:1*/, 0xF, 0xF, false);
    return __int_as_float(r);
}

// ---------------------------------------------------------------------------
// Fused producer/consumer.
// Blocks 0..7: scanners (one wave per b). Blocks 8..: producers in (t,b,n)-
// major order so the t-frontier advances uniformly across all b.
// Producers: emission+transition fold, sc1 stores -> LLC, __syncthreads
// (vmcnt drain), RELAXED per-(t,b) flag atomicAdd.
// Scanners: confirm flags one 8-window ahead via fetch_add(0) RMWs (coherent,
// ~700cy, latency hidden); SE/ME via PLAIN float4 loads -- those lines are
// first touched only after the flag confirms, so they fill fresh from LLC.
// ---------------------------------------------------------------------------
__global__ __launch_bounds__(256, 5) void fused_kernel(
    const float* __restrict__ mels,   // (B,T,D)
    const float* __restrict__ means,  // (B,T,N,D)
    const float* __restrict__ stds,   // (B,T,N,D)
    const float* __restrict__ tv,     // (B,T,N)
    const int* __restrict__ inputs_len,
    const int* __restrict__ mel_lens,
    float* __restrict__ SE,           // (B,T,N) ws
    float* __restrict__ ME,           // (B,T,N) ws
    unsigned* __restrict__ flags,     // (T,B) ws, pre-zeroed; idx = t*NB+b
    float* __restrict__ out)          // (B,)
{
    if (blockIdx.x >= NB) {
        // ----------------------------- producer -----------------------------
        const int tid = threadIdx.x;
        const int G = (blockIdx.x - NB) * 64 + (tid >> 2);  // (t,b,n)-major row
        const int q = tid & 3;
        const int t = G / (NB * NN);
        const int rb = G - t * (NB * NN);
        const int b = rb / NN;
        const int n = rb - b * NN;
        const int ml = mel_lens[b];
        const int il = inputs_len[b];
        const int R = (b * NT + t) * NN + n;                // (b,t,n) storage idx

        if (t < ml) {
            if (n >= il) {
                if (q == 0) { A_STF(&SE[R], BIG_NEG); A_STF(&ME[R], BIG_NEG); }
            } else {
                const float4* mp = reinterpret_cast<const float4*>(means) + (size_t)R * (ND / 4) + q;
                const float4* sp = reinterpret_cast<const float4*>(stds)  + (size_t)R * (ND / 4) + q;
                const float4* xp = reinterpret_cast<const float4*>(mels)  + (size_t)(b * NT + t) * (ND / 4) + q;
                float acc = 0.f;    // sum z^2
                float prod = 1.f;   // prod of 20 stds in [9.5e-7, 3325]: safe
#pragma unroll
                for (int k = 0; k < ND / 16; ++k) {
                    const float4 m = mp[k * 4];
                    const float4 s = sp[k * 4];
                    const float4 x = xp[k * 4];
                    float z0 = __fdividef(x.x - m.x, s.x);
                    float z1 = __fdividef(x.y - m.y, s.y);
                    float z2 = __fdividef(x.z - m.z, s.z);
                    float z3 = __fdividef(x.w - m.w, s.w);
                    acc = fmaf(z0, z0, acc);
                    acc = fmaf(z1, z1, acc);
                    acc = fmaf(z2, z2, acc);
                    acc = fmaf(z3, z3, acc);
                    prod *= s.x * s.y * s.z * s.w;
                }
                acc = fmaf(acc, HALF_LOG2E, hw_log2(prod));
                acc += __shfl_xor(acc, 1);
                acc += __shfl_xor(acc, 2);
                if (q == 0) {
                    const float e2 = -acc - D_HALF_L2PI;
                    if (t == 0) {
                        A_STF(&SE[R], e2);        // raw e2; only n==0 consumed
                        A_STF(&ME[R], BIG_NEG);
                    } else {
                        float w = tv[R] * LOG2E;
                        float stay2 = -(fmaxf(w, 0.f) + softplus2(w));     // log2 sig(-v)
                        A_STF(&SE[R], e2 + fmaxf(stay2, L2EPS));
                        if (n == 0) {
                            A_STF(&ME[R], BIG_NEG);
                        } else {
                            float u = tv[R - 1] * LOG2E;
                            float mv2 = -(fmaxf(-u, 0.f) + softplus2(u));  // log2 sig(v)
                            A_STF(&ME[R], e2 + fmaxf(mv2, L2EPS));
                        }
                    }
                }
            }
        }
        __syncthreads();   // s_waitcnt vmcnt(0) before s_barrier -> sc1 stores at LLC
        if (tid == 0) {
            const int G0 = (blockIdx.x - NB) * 64;
            const int g0 = G0 / NN, g1 = (G0 + 63) / NN;   // (t*NB+b) group ids
            if (g0 == g1) {
                A_ADD(&flags[g0], 64u);
            } else {
                unsigned c0 = (unsigned)((g0 + 1) * NN - G0);
                A_ADD(&flags[g0], c0);
                A_ADD(&flags[g1], 64u - c0);
            }
        }
        return;
    }

    // ------------------------------- scanner --------------------------------
    const int b = blockIdx.x;
    if (threadIdx.x >= 64) return;
    const int lane = threadIdx.x;
    const int il = inputs_len[b];
    const int ml = mel_lens[b];
    const int mlm1 = ml - 1;
    const int cl = (lane < NN / 4) ? lane : (NN / 4 - 1);

    const float* seb = SE + (size_t)b * NT * NN;
    const float* meb = ME + (size_t)b * NT * NN;
    const float* vb  = tv + (size_t)b * NT * NN;
    unsigned* flgb = flags + b;            // flag for time T at flgb[T*NB]

    unsigned fv0, fv1, fv2, fv3, fv4, fv5, fv6, fv7;
#define FLD(K, TT) fv##K = ((TT) < ml) ? A_RMW0(flgb + (size_t)(TT) * NB) : (unsigned)NN;
#define FCHK(K, TT) if ((TT) < ml) { while (fv##K < (unsigned)NN) fv##K = A_RMW0(flgb + (size_t)(TT) * NB); }
#define F8(OP, T0) OP(0,(T0)) OP(1,(T0)+1) OP(2,(T0)+2) OP(3,(T0)+3) \
                   OP(4,(T0)+4) OP(5,(T0)+5) OP(6,(T0)+6) OP(7,(T0)+7)

    // prologue: confirm flags 0..8, leave fv = issued RMWs for [9,17)
    F8(FLD, 0) F8(FCHK, 0)
    FLD(0, 8) FCHK(0, 8)
    asm volatile("" ::: "memory");
    F8(FLD, 9)

    auto ld4 = [cl](const float* p) { return reinterpret_cast<const float4*>(p)[cl]; };
#define LDT(TT) ((size_t)(((TT) <= mlm1) ? (TT) : mlm1) * NN)

    // depth-8 slots: slot K holds t = base+K, base starts at 1 (ml >= 200)
#define PREL(K, TT) \
    float4 se##K = ld4(seb + LDT(TT)); \
    float4 me##K = ld4(meb + LDT(TT));
    PREL(0, 1) PREL(1, 2) PREL(2, 3) PREL(3, 4)
    PREL(4, 5) PREL(5, 6) PREL(6, 7) PREL(7, 8)
#undef PREL

    // init t=0: only state 0 finite (prior); SE[b][0][0] holds raw e2
    float la0 = (lane == 0) ? seb[0] : BIG_NEG;
    float la1 = BIG_NEG, la2 = BIG_NEG, la3 = BIG_NEG;

#define STEPBODY(SEV, MEV) { \
        float carry = wave_shr1(la3, BIG_NEG); \
        float a0 = la0 + SEV.x, c0 = carry + MEV.x; \
        float a1 = la1 + SEV.y, c1 = la0 + MEV.y; \
        float a2 = la2 + SEV.z, c2 = la1 + MEV.z; \
        float a3 = la3 + SEV.w, c3 = la2 + MEV.w; \
        la0 = l2add(a0, c0); la1 = l2add(a1, c1); \
        la2 = l2add(a2, c2); la3 = l2add(a3, c3); }

#define STEP(K, TT) { \
        float4 se_ = se##K, me_ = me##K; \
        se##K = ld4(seb + LDT((TT) + 8)); \
        me##K = ld4(meb + LDT((TT) + 8)); \
        STEPBODY(se_, me_) }

#define TSTEP(K) if (t + (K) < ml) { STEPBODY(se##K, me##K) }

    int t = 1;
    for (; t + 7 < ml; t += 8) {
        // confirm flags [t+8, t+16) (RMWs issued one window ago), issue [t+16, t+24)
        F8(FCHK, t + 8)
        asm volatile("" ::: "memory");
        F8(FLD, t + 16)
        STEP(0, t)     STEP(1, t + 1) STEP(2, t + 2) STEP(3, t + 3)
        STEP(4, t + 4) STEP(5, t + 5) STEP(6, t + 6) STEP(7, t + 7)
    }
    // tail (<= 7 steps): slots hold t..t+7, flags already confirmed
    TSTEP(0) TSTEP(1) TSTEP(2) TSTEP(3) TSTEP(4) TSTEP(5) TSTEP(6)

#undef FLD
#undef FCHK
#undef F8
#undef LDT
#undef STEPBODY
#undef STEP
#undef TSTEP

    // final: only state il-1 contributes
    const int fin = il - 1;
    const int n0 = lane * 4;
    if (fin >= n0 && fin < n0 + 4) {
        float w = vb[(size_t)mlm1 * NN + fin] * LOG2E;
        float lmove2 = fmaxf(-(fmaxf(-w, 0.f) + softplus2(w)), L2EPS);
        float lastla = (fin == n0)     ? la0
                     : (fin == n0 + 1) ? la1
                     : (fin == n0 + 2) ? la2
                                       : la3;
        out[b] = LN2 * (lastla + lmove2);
    }
}

extern "C" void kernel_launch(void* const* d_in, const int* in_sizes, int n_in,
                              void* d_out, int out_size, void* d_ws, size_t ws_size,
                              hipStream_t stream) {
    const float* mels  = (const float*)d_in[0];
    const float* means = (const float*)d_in[1];
    const float* stds  = (const float*)d_in[2];
    const float* tv    = (const float*)d_in[3];
    const int* inputs_len = (const int*)d_in[4];
    const int* mel_lens   = (const int*)d_in[5];
    float* out = (float*)d_out;

    float* SE = (float*)d_ws;                           // B*T*N floats
    float* ME = SE + (size_t)NROWS;                     // B*T*N floats
    unsigned* flags = (unsigned*)(ME + (size_t)NROWS);  // T*B uints (12.8 KB)

    hipMemsetAsync(flags, 0, (size_t)NT * NB * sizeof(unsigned), stream);
    fused_kernel<<<dim3(PRODB + NB), dim3(256), 0, stream>>>(
        mels, means, stds, tv, inputs_len, mel_lens, SE, ME, flags, out);
}

// Round 11
// 92.370 us; speedup vs baseline: 5.8723x; 1.5072x over previous
//
#include <hip/hip_runtime.h>

#define NB 8
#define NT 400
#define NN 200
#define ND 80
#define NC (ND / 4)            // 20 float4 chunks per row
#define CHUNKS (NN * NC)       // 4000 chunks per (b,t) tile
#define LDSW 21                // padded row stride in LDS (kills bank conflicts)

static constexpr float BIG_NEG = -1e30f;
static constexpr float LN2 = 0.6931471805599453f;
static constexpr float LOG2E = 1.4426950408889634f;
static constexpr float L2EPS = -99.65784284662087f;        // log(1e-30)*LOG2E
static constexpr float HALF_LOG2E = 0.7213475204444817f;   // 0.5*LOG2E
static constexpr float D_HALF_L2PI = 106.05984517680935f;  // D*0.5*log2(2pi)

static __device__ __forceinline__ float hw_exp2(float x) { return __builtin_amdgcn_exp2f(x); }
static __device__ __forceinline__ float hw_log2(float x) { return __builtin_amdgcn_logf(x); }

// exact log2(2^a + 2^b); used outside the serial loop
static __device__ __forceinline__ float l2add(float a, float b) {
    float mx = fmaxf(a, b);
    float d = fminf(a, b) - mx;  // <= 0
    return mx + hw_log2(1.0f + hw_exp2(d));
}

// fast log2(2^x + 2^y): 1 trans + cubic for log2(1+u), u in [0,1].
// Exact at u=0,1; max err ~+0.011 log2-units. Validated absmax 0.0 in R7.
static __device__ __forceinline__ float pl2add(float x, float y) {
    float mx = fmaxf(x, y);
    float d = fminf(x, y) - mx;            // <= 0
    float u = hw_exp2(d);                  // 2^d in [0,1]
    float p = fmaf(0.1177f, u, -0.5604f);
    p = fmaf(p, u, 1.4427f);
    return fmaf(u, p, mx);                 // mx + log2(1+u) approx
}

// log2(1 + 2^-|w|), in [0,1]
static __device__ __forceinline__ float softplus2(float w) {
    return hw_log2(1.0f + hw_exp2(-fabsf(w)));
}

// whole-wave shift right by 1 lane via DPP; lane 0 receives `fill`
static __device__ __forceinline__ float wave_shr1(float x, float fill) {
    int r = __builtin_amdgcn_update_dpp(__float_as_int(fill), __float_as_int(x),
                                        0x138 /*wave_shr:1*/, 0xF, 0xF, false);
    return __int_as_float(r);
}

// ---------------------------------------------------------------------------
// Kernel 1: one block per (b,t) tile. Loads the 64KB means + 64KB stds tiles
// with fully-coalesced wave loads (64 lanes x 16B = 1KB/instr, 8 L1 lines --
// vs the old quad-per-row layout's 16 x 64B fragments straddling ~32 lines).
// Per-chunk partials (sum z^2, prod s) go to padded LDS; 200 threads then
// reduce rows and fold the transition terms:
//   SE[t][n] = e2 + log2(sigmoid(-tv[t][n]))      (stay)
//   ME[t][n] = e2 + log2(sigmoid( tv[t][n-1]))    (move, pre-shifted)
// ---------------------------------------------------------------------------
__global__ __launch_bounds__(256) void emission_kernel(
    const float* __restrict__ mels,   // (B,T,D)
    const float* __restrict__ means,  // (B,T,N,D)
    const float* __restrict__ stds,   // (B,T,N,D)
    const float* __restrict__ tv,     // (B,T,N)
    const int* __restrict__ inputs_len,
    const int* __restrict__ mel_lens,
    float* __restrict__ SE,           // (B,T,N) workspace
    float* __restrict__ ME)           // (B,T,N) workspace
{
    const int bt = blockIdx.x;        // b*NT + t
    const int b = bt / NT;
    const int t = bt - b * NT;
    const int ml = mel_lens[b];
    if (t >= ml) return;              // never consumed
    const int il = inputs_len[b];

    __shared__ float sz[NN * LDSW];   // per-chunk sum of z^2 (padded rows)
    __shared__ float pr[NN * LDSW];   // per-chunk prod of stds

    const int tid = threadIdx.x;
    const float4* m4 = reinterpret_cast<const float4*>(means) + (size_t)bt * CHUNKS;
    const float4* s4 = reinterpret_cast<const float4*>(stds)  + (size_t)bt * CHUNKS;
    const float4* x4 = reinterpret_cast<const float4*>(mels)  + (size_t)bt * NC;

#pragma unroll
    for (int j = 0; j < 16; ++j) {
        const int c = tid + 256 * j;            // chunk id in [0, 4000)
        if (c < CHUNKS) {
            const int n = c / NC;               // row
            const int dk = c - n * NC;          // chunk within row
            const float4 m = m4[c];
            const float4 s = s4[c];
            const float4 x = x4[dk];
            float z0 = __fdividef(x.x - m.x, s.x);
            float z1 = __fdividef(x.y - m.y, s.y);
            float z2 = __fdividef(x.z - m.z, s.z);
            float z3 = __fdividef(x.w - m.w, s.w);
            float zz = z0 * z0;
            zz = fmaf(z1, z1, zz);
            zz = fmaf(z2, z2, zz);
            zz = fmaf(z3, z3, zz);
            sz[n * LDSW + dk] = zz;
            pr[n * LDSW + dk] = s.x * s.y * s.z * s.w;
        }
    }
    __syncthreads();

    if (tid < NN) {
        const int n = tid;
        const size_t R = (size_t)bt * NN + n;
        if (n >= il) {
            SE[R] = BIG_NEG;
            ME[R] = BIG_NEG;
            return;
        }
        float sum = 0.f;
        float prod = 1.f;   // prod of 80 stds in [0.5,1.5]^80 ~ [8e-25,1.2e14]: safe
#pragma unroll
        for (int j = 0; j < NC; ++j) {
            sum += sz[n * LDSW + j];
            prod *= pr[n * LDSW + j];
        }
        const float e2 = -fmaf(sum, HALF_LOG2E, hw_log2(prod)) - D_HALF_L2PI;

        if (t == 0) {
            SE[R] = e2;      // raw (log2-scaled) emission; only n==0 consumed
            ME[R] = BIG_NEG;
        } else {
            float w = tv[R] * LOG2E;
            float stay2 = -(fmaxf(w, 0.f) + softplus2(w));     // log2 sigmoid(-v)
            SE[R] = e2 + fmaxf(stay2, L2EPS);
            if (n == 0) {
                ME[R] = BIG_NEG;
            } else {
                float u = tv[R - 1] * LOG2E;
                float mv2 = -(fmaxf(-u, 0.f) + softplus2(u));  // log2 sigmoid(v)
                ME[R] = e2 + fmaxf(mv2, L2EPS);
            }
        }
    }
}

// ---------------------------------------------------------------------------
// Kernel 2: unnormalized forward recursion in log2 domain, prefetch depth 16,
// fast pl2add in the serial chain (R7-validated).
//   la[n] <- pl2add(la[n] + SE[t][n], la[n-1] + ME[t][n])
// One wave per b; lane l holds states 4l..4l+3; DPP wave_shr for the carry.
// ---------------------------------------------------------------------------
__global__ __launch_bounds__(64) void scan_kernel(
    const float* __restrict__ SE,     // (B,T,N)
    const float* __restrict__ ME,     // (B,T,N)
    const float* __restrict__ tv,     // (B,T,N)
    const int* __restrict__ inputs_len,
    const int* __restrict__ mel_lens,
    float* __restrict__ out)          // (B,)
{
    const int b = blockIdx.x;
    const int lane = threadIdx.x;
    const int il = inputs_len[b];
    const int ml = mel_lens[b];
    const int mlm1 = ml - 1;
    const int cl = (lane < NN / 4) ? lane : (NN / 4 - 1);  // clamp: loads in-bounds

    const float* seb = SE + (size_t)b * NT * NN;
    const float* meb = ME + (size_t)b * NT * NN;
    const float* vb  = tv + (size_t)b * NT * NN;

    float la0 = (lane == 0) ? seb[0] : BIG_NEG;
    float la1 = BIG_NEG, la2 = BIG_NEG, la3 = BIG_NEG;

    auto ld4 = [cl](const float* p) { return reinterpret_cast<const float4*>(p)[cl]; };
#define LDT(TT) ((size_t)(((TT) <= mlm1) ? (TT) : mlm1) * NN)

// ordered S = 1..15,0 so OP(S, TT) pairs slot S with time TT, TT%16==S
#define SLOT16(OP, T0) \
    OP(1,(T0))     OP(2,(T0)+1)  OP(3,(T0)+2)  OP(4,(T0)+3)  \
    OP(5,(T0)+4)  OP(6,(T0)+5)  OP(7,(T0)+6)  OP(8,(T0)+7)  \
    OP(9,(T0)+8)  OP(10,(T0)+9) OP(11,(T0)+10) OP(12,(T0)+11) \
    OP(13,(T0)+12) OP(14,(T0)+13) OP(15,(T0)+14) OP(0,(T0)+15)

#define PRELOAD(S, TT) \
    float4 se##S = ld4(seb + LDT(TT)); \
    float4 me##S = ld4(meb + LDT(TT));
    // preload t = 1..16 (ml >= 200 so always valid times)
    SLOT16(PRELOAD, 1)
#undef PRELOAD

#define STEPBODY(SEV, MEV) { \
        float carry = wave_shr1(la3, BIG_NEG); \
        float a0 = la0 + SEV.x, c0 = carry + MEV.x; \
        float a1 = la1 + SEV.y, c1 = la0 + MEV.y; \
        float a2 = la2 + SEV.z, c2 = la1 + MEV.z; \
        float a3 = la3 + SEV.w, c3 = la2 + MEV.w; \
        la0 = pl2add(a0, c0); la1 = pl2add(a1, c1); \
        la2 = pl2add(a2, c2); la3 = pl2add(a3, c3); }

#define STEP(S, TT) { \
        float4 se_ = se##S, me_ = me##S; \
        se##S = ld4(seb + LDT((TT) + 16)); \
        me##S = ld4(meb + LDT((TT) + 16)); \
        STEPBODY(se_, me_) }

#define TSTEP(S, TT) if ((TT) < ml) { STEPBODY(se##S, me##S) }

    int t = 1;
    for (; t + 15 < ml; t += 16) {
        SLOT16(STEP, t)
    }
    SLOT16(TSTEP, t)   // tail: <= 15 remaining steps, slots hold t..t+15

#undef SLOT16
#undef STEP
#undef TSTEP
#undef STEPBODY
#undef LDT

    // final: only state il-1 contributes
    const int fin = il - 1;
    const int n0 = lane * 4;
    if (fin >= n0 && fin < n0 + 4) {
        float w = vb[(size_t)mlm1 * NN + fin] * LOG2E;
        float lmove2 = fmaxf(-(fmaxf(-w, 0.f) + softplus2(w)), L2EPS);
        float lastla = (fin == n0)     ? la0
                     : (fin == n0 + 1) ? la1
                     : (fin == n0 + 2) ? la2
                                       : la3;
        out[b] = LN2 * (lastla + lmove2);
    }
}

extern "C" void kernel_launch(void* const* d_in, const int* in_sizes, int n_in,
                              void* d_out, int out_size, void* d_ws, size_t ws_size,
                              hipStream_t stream) {
    const float* mels  = (const float*)d_in[0];
    const float* means = (const float*)d_in[1];
    const float* stds  = (const float*)d_in[2];
    const float* tv    = (const float*)d_in[3];
    const int* inputs_len = (const int*)d_in[4];
    const int* mel_lens   = (const int*)d_in[5];
    float* out = (float*)d_out;

    float* SE = (float*)d_ws;                    // B*T*N floats = 2.56 MB
    float* ME = SE + (size_t)NB * NT * NN;       // B*T*N floats = 2.56 MB

    emission_kernel<<<dim3(NB * NT), dim3(256), 0, stream>>>(
        mels, means, stds, tv, inputs_len, mel_lens, SE, ME);
    scan_kernel<<<dim3(NB), dim3(64), 0, stream>>>(
        SE, ME, tv, inputs_len, mel_lens, out);
}

// Round 12
// 76.811 us; speedup vs baseline: 7.0618x; 1.2026x over previous
//
#include <hip/hip_runtime.h>

#define NB 8
#define NT 400
#define NN 200
#define ND 80

static constexpr float BIG_NEG = -1e30f;
static constexpr float LN2 = 0.6931471805599453f;
static constexpr float LOG2E = 1.4426950408889634f;
static constexpr float L2EPS = -99.65784284662087f;        // log(1e-30)*LOG2E
static constexpr float HALF_LOG2E = 0.7213475204444817f;   // 0.5*LOG2E
static constexpr float D_HALF_L2PI = 106.05984517680935f;  // D*0.5*log2(2pi)

static __device__ __forceinline__ float hw_exp2(float x) { return __builtin_amdgcn_exp2f(x); }
static __device__ __forceinline__ float hw_log2(float x) { return __builtin_amdgcn_logf(x); }

// fast log2(2^x + 2^y): 1 trans + cubic for log2(1+u), u in [0,1].
// Exact at u=0,1; max err ~+0.011 log2-units (one-sided). Serial-path use
// validated in R7/R11 (absmax 0.0). Cuts per-step trans issue 64->32 cy.
static __device__ __forceinline__ float pl2add(float x, float y) {
    float mx = fmaxf(x, y);
    float d = fminf(x, y) - mx;            // <= 0
    float u = hw_exp2(d);                  // 2^d in [0,1]
    float p = fmaf(0.1177f, u, -0.5604f);
    p = fmaf(p, u, 1.4427f);
    return fmaf(u, p, mx);                 // mx + log2(1+u) approx
}

// log2(1 + 2^-|w|), in [0,1] (exact; parallel paths only)
static __device__ __forceinline__ float softplus2(float w) {
    return hw_log2(1.0f + hw_exp2(-fabsf(w)));
}

// whole-wave shift right by 1 lane via DPP; lane 0 receives `fill`
static __device__ __forceinline__ float wave_shr1(float x, float fill) {
    int r = __builtin_amdgcn_update_dpp(__float_as_int(fill), __float_as_int(x),
                                        0x138 /*wave_shr:1*/, 0xF, 0xF, false);
    return __int_as_float(r);
}

// ---------------------------------------------------------------------------
// Kernel 1 (log2 domain) -- BYTE-IDENTICAL structure to the 79.5us R6 version.
//   SE[t][n] = e2 + log2(sigmoid(-tv[t][n]))      (stay)
//   ME[t][n] = e2 + log2(sigmoid( tv[t][n-1]))    (move, pre-shifted)
// log2(std) summed as log2(prod(std)) -- one v_log_f32 per lane.
// ---------------------------------------------------------------------------
__global__ __launch_bounds__(256) void emission_kernel(
    const float* __restrict__ mels,   // (B,T,D)
    const float* __restrict__ means,  // (B,T,N,D)
    const float* __restrict__ stds,   // (B,T,N,D)
    const float* __restrict__ tv,     // (B,T,N)
    const int* __restrict__ inputs_len,
    const int* __restrict__ mel_lens,
    float* __restrict__ SE,           // (B,T,N) workspace
    float* __restrict__ ME)           // (B,T,N) workspace
{
    const int tid = threadIdx.x;
    const int R = blockIdx.x * 64 + (tid >> 2);  // row in [0, B*T*N)
    const int q = tid & 3;
    const int b = R / (NT * NN);
    const int r2 = R - b * (NT * NN);
    const int t = r2 / NN;
    const int n = r2 - t * NN;

    if (t >= mel_lens[b]) return;
    if (n >= inputs_len[b]) {
        if (q == 0) { SE[R] = BIG_NEG; ME[R] = BIG_NEG; }
        return;
    }

    const float4* mp = reinterpret_cast<const float4*>(means) + (size_t)R * (ND / 4) + q;
    const float4* sp = reinterpret_cast<const float4*>(stds)  + (size_t)R * (ND / 4) + q;
    const float4* xp = reinterpret_cast<const float4*>(mels)  + (size_t)(b * NT + t) * (ND / 4) + q;

    float acc = 0.f;    // sum of HALF_LOG2E * z^2
    float prod = 1.f;   // prod of 20 stds in [9.5e-7, 3325]: safe
#pragma unroll
    for (int k = 0; k < ND / 16; ++k) {
        const float4 m = mp[k * 4];
        const float4 s = sp[k * 4];
        const float4 x = xp[k * 4];
        float z0 = __fdividef(x.x - m.x, s.x);
        float z1 = __fdividef(x.y - m.y, s.y);
        float z2 = __fdividef(x.z - m.z, s.z);
        float z3 = __fdividef(x.w - m.w, s.w);
        acc = fmaf(z0 * HALF_LOG2E, z0, acc);
        acc = fmaf(z1 * HALF_LOG2E, z1, acc);
        acc = fmaf(z2 * HALF_LOG2E, z2, acc);
        acc = fmaf(z3 * HALF_LOG2E, z3, acc);
        prod *= s.x * s.y * s.z * s.w;
    }
    acc += hw_log2(prod);
    acc += __shfl_xor(acc, 1);
    acc += __shfl_xor(acc, 2);

    if (q == 0) {
        const float e2 = -acc - D_HALF_L2PI;
        if (t == 0) {
            SE[R] = e2;              // raw (log2-scaled) emission; only n==0 used
            ME[R] = BIG_NEG;
        } else {
            const size_t base = (size_t)b * NT * NN + (size_t)t * NN;
            float w = tv[base + n] * LOG2E;
            float stay2 = -(fmaxf(w, 0.f) + softplus2(w));     // log2 sigmoid(-v)
            SE[R] = e2 + fmaxf(stay2, L2EPS);
            if (n == 0) {
                ME[R] = BIG_NEG;
            } else {
                float u = tv[base + n - 1] * LOG2E;
                float mv2 = -(fmaxf(-u, 0.f) + softplus2(u));  // log2 sigmoid(v)
                ME[R] = e2 + fmaxf(mv2, L2EPS);
            }
        }
    }
}

// ---------------------------------------------------------------------------
// Kernel 2: R6's depth-16 scan with the single change l2add -> pl2add.
//   la[n] <- pl2add(la[n] + SE[t][n], la[n-1] + ME[t][n])
// One wave per b; lane l holds states 4l..4l+3; DPP wave_shr for the carry.
// ---------------------------------------------------------------------------
__global__ __launch_bounds__(64) void scan_kernel(
    const float* __restrict__ SE,     // (B,T,N)
    const float* __restrict__ ME,     // (B,T,N)
    const float* __restrict__ tv,     // (B,T,N)
    const int* __restrict__ inputs_len,
    const int* __restrict__ mel_lens,
    float* __restrict__ out)          // (B,)
{
    const int b = blockIdx.x;
    const int lane = threadIdx.x;
    const int il = inputs_len[b];
    const int ml = mel_lens[b];
    const int mlm1 = ml - 1;
    const int cl = (lane < NN / 4) ? lane : (NN / 4 - 1);  // clamp: loads in-bounds

    const float* seb = SE + (size_t)b * NT * NN;
    const float* meb = ME + (size_t)b * NT * NN;
    const float* vb  = tv + (size_t)b * NT * NN;

    float la0 = (lane == 0) ? seb[0] : BIG_NEG;
    float la1 = BIG_NEG, la2 = BIG_NEG, la3 = BIG_NEG;

    auto ld4 = [cl](const float* p) { return reinterpret_cast<const float4*>(p)[cl]; };
#define LDT(TT) ((size_t)(((TT) <= mlm1) ? (TT) : mlm1) * NN)

// ordered S = 1..15,0 so OP(S, TT) pairs slot S with time TT, TT%16==S
#define SLOT16(OP, T0) \
    OP(1,(T0))     OP(2,(T0)+1)  OP(3,(T0)+2)  OP(4,(T0)+3)  \
    OP(5,(T0)+4)  OP(6,(T0)+5)  OP(7,(T0)+6)  OP(8,(T0)+7)  \
    OP(9,(T0)+8)  OP(10,(T0)+9) OP(11,(T0)+10) OP(12,(T0)+11) \
    OP(13,(T0)+12) OP(14,(T0)+13) OP(15,(T0)+14) OP(0,(T0)+15)

#define PRELOAD(S, TT) \
    float4 se##S = ld4(seb + LDT(TT)); \
    float4 me##S = ld4(meb + LDT(TT));
    // preload t = 1..16 (ml >= 200 so always valid times)
    SLOT16(PRELOAD, 1)
#undef PRELOAD

#define STEPBODY(SEV, MEV) { \
        float carry = wave_shr1(la3, BIG_NEG); \
        float a0 = la0 + SEV.x, c0 = carry + MEV.x; \
        float a1 = la1 + SEV.y, c1 = la0 + MEV.y; \
        float a2 = la2 + SEV.z, c2 = la1 + MEV.z; \
        float a3 = la3 + SEV.w, c3 = la2 + MEV.w; \
        la0 = pl2add(a0, c0); la1 = pl2add(a1, c1); \
        la2 = pl2add(a2, c2); la3 = pl2add(a3, c3); }

#define STEP(S, TT) { \
        float4 se_ = se##S, me_ = me##S; \
        se##S = ld4(seb + LDT((TT) + 16)); \
        me##S = ld4(meb + LDT((TT) + 16)); \
        STEPBODY(se_, me_) }

#define TSTEP(S, TT) if ((TT) < ml) { STEPBODY(se##S, me##S) }

    int t = 1;
    for (; t + 15 < ml; t += 16) {
        SLOT16(STEP, t)
    }
    SLOT16(TSTEP, t)   // tail: <= 15 remaining steps, slots hold t..t+15

#undef SLOT16
#undef STEP
#undef TSTEP
#undef STEPBODY
#undef LDT

    // final: only state il-1 contributes
    const int fin = il - 1;
    const int n0 = lane * 4;
    if (fin >= n0 && fin < n0 + 4) {
        float w = vb[(size_t)mlm1 * NN + fin] * LOG2E;
        float lmove2 = fmaxf(-(fmaxf(-w, 0.f) + softplus2(w)), L2EPS);
        float lastla = (fin == n0)     ? la0
                     : (fin == n0 + 1) ? la1
                     : (fin == n0 + 2) ? la2
                                       : la3;
        out[b] = LN2 * (lastla + lmove2);
    }
}

extern "C" void kernel_launch(void* const* d_in, const int* in_sizes, int n_in,
                              void* d_out, int out_size, void* d_ws, size_t ws_size,
                              hipStream_t stream) {
    const float* mels  = (const float*)d_in[0];
    const float* means = (const float*)d_in[1];
    const float* stds  = (const float*)d_in[2];
    const float* tv    = (const float*)d_in[3];
    const int* inputs_len = (const int*)d_in[4];
    const int* mel_lens   = (const int*)d_in[5];
    float* out = (float*)d_out;

    float* SE = (float*)d_ws;                    // B*T*N floats = 2.56 MB
    float* ME = SE + (size_t)NB * NT * NN;       // B*T*N floats = 2.56 MB

    const int rows = NB * NT * NN;               // 640000
    emission_kernel<<<dim3(rows / 64), dim3(256), 0, stream>>>(
        mels, means, stds, tv, inputs_len, mel_lens, SE, ME);
    scan_kernel<<<dim3(NB), dim3(64), 0, stream>>>(
        SE, ME, tv, inputs_len, mel_lens, out);
}